// Round 12
// baseline (245.264 us; speedup 1.0000x reference)
//
#include <hip/hip_runtime.h>
#include <hip/hip_bf16.h>
#include <cmath>

typedef __bf16 bf16_t;
typedef __attribute__((ext_vector_type(8))) __bf16 bf16x8;
typedef __attribute__((ext_vector_type(4))) float f32x4;
typedef __attribute__((ext_vector_type(4))) short s16x4;

#define S_LEN 2048
#define DMODEL 2048
#define KVDIM 512
#define NHEADS 32
#define NKV 8
#define HDIM 64

__device__ inline f32x4 zero4() { f32x4 z; z[0]=0.f; z[1]=0.f; z[2]=0.f; z[3]=0.f; return z; }

// Inputs are fp32 (established R2-R6: bf16 misread would NaN; we pass at 1.46e-3).
// One dispatch converts all 5 tensors to bf16. 2048 elems/block:
// x 2048 | Wq 2048 | Wk 512 | Wv 512 | Wo 2048 blocks (7168 total).
__global__ void convert_all(const float* __restrict__ s0, bf16_t* __restrict__ d0,
                            const float* __restrict__ s1, bf16_t* __restrict__ d1,
                            const float* __restrict__ s2, bf16_t* __restrict__ d2,
                            const float* __restrict__ s3, bf16_t* __restrict__ d3,
                            const float* __restrict__ s4, bf16_t* __restrict__ d4) {
  int b = blockIdx.x;
  const float* src; bf16_t* dst; int boff;
  if      (b < 2048) { src = s0; dst = d0; boff = b; }
  else if (b < 4096) { src = s1; dst = d1; boff = b - 2048; }
  else if (b < 4608) { src = s2; dst = d2; boff = b - 4096; }
  else if (b < 5120) { src = s3; dst = d3; boff = b - 4608; }
  else               { src = s4; dst = d4; boff = b - 5120; }
  int idx = (boff * 256 + threadIdx.x) * 8;
  bf16x8 v;
#pragma unroll
  for (int j = 0; j < 8; j++) v[j] = (bf16_t)src[idx + j];
  *(bf16x8*)(dst + idx) = v;
}

// GEMM core, R17/R18: 64x64 tiles (was 128x64). R9's counters isolated the
// GEMM limiter: staging loads L2-miss (~900cy) and 2-3 blocks/CU can't keep
// enough misses in flight (FETCH 66.7MB at 900GB/s, MfmaUtil 11-15%, Occ 16%).
// m102: same structure at 4 blocks/CU (N=4096) runs 2.6x faster -- resident-
// block TLP is the lever (split-K R6 and manual vmcnt R9 both failed to
// substitute). 64x64: LDS 16KB, acc 16 VGPR/wave -> ~8 blocks/CU, zero extra
// HBM traffic. R18 fixes R11's vT grid bug (vT is 512x2048 -> 8x32=256 blocks,
// not 1024; bm overran the 512-row matrix and trampled kb/vb/Wob -> absmax 410).
template <bool F32OUT, bool ROPE>
__device__ __forceinline__ void gemm_core(const bf16_t* __restrict__ A,
                                          const bf16_t* __restrict__ Bt,
                                          void* __restrict__ Cout,
                                          int N, int K, int bm, int bn,
                                          bf16_t* __restrict__ smem) {
  bf16_t* As = smem;               // 64 x 64 (8KB)
  bf16_t* Bs = smem + 64 * 64;     // 64 x 64 (8KB)
  const int tid  = threadIdx.x;
  const int wave = tid >> 6, lane = tid & 63;
  const int wm = wave >> 1, wn = wave & 1;
  const int quad = lane >> 4, lr = lane & 15;
  const int srow = lane >> 3, scol = lane & 7;

  f32x4 acc[2][2];
#pragma unroll
  for (int i = 0; i < 2; i++)
#pragma unroll
    for (int j = 0; j < 2; j++) acc[i][j] = zero4();

  for (int k0 = 0; k0 < K; k0 += 64) {
#pragma unroll
    for (int i = 0; i < 2; i++) {
      const bf16_t* gA = A + (size_t)(bm + i * 32 + wave * 8 + srow) * K + k0 + scol * 8;
      bf16_t* lA = As + (i * 32 + wave * 8) * 64;
      __builtin_amdgcn_global_load_lds((const __attribute__((address_space(1))) void*)gA,
                                       (__attribute__((address_space(3))) void*)lA, 16, 0, 0);
    }
#pragma unroll
    for (int i = 0; i < 2; i++) {
      const bf16_t* gB = Bt + (size_t)(bn + i * 32 + wave * 8 + srow) * K + k0 + scol * 8;
      bf16_t* lB = Bs + (i * 32 + wave * 8) * 64;
      __builtin_amdgcn_global_load_lds((const __attribute__((address_space(1))) void*)gB,
                                       (__attribute__((address_space(3))) void*)lB, 16, 0, 0);
    }
    __syncthreads();
#pragma unroll
    for (int ks = 0; ks < 2; ks++) {
      bf16x8 a[2], b[2];
#pragma unroll
      for (int mt = 0; mt < 2; mt++)
        a[mt] = *(const bf16x8*)&As[(wm * 32 + mt * 16 + lr) * 64 + ks * 32 + quad * 8];
#pragma unroll
      for (int nt = 0; nt < 2; nt++)
        b[nt] = *(const bf16x8*)&Bs[(wn * 32 + nt * 16 + lr) * 64 + ks * 32 + quad * 8];
#pragma unroll
      for (int mt = 0; mt < 2; mt++)
#pragma unroll
        for (int nt = 0; nt < 2; nt++)
          acc[mt][nt] = __builtin_amdgcn_mfma_f32_16x16x32_bf16(a[mt], b[nt], acc[mt][nt], 0, 0, 0);
    }
    __syncthreads();
  }

  if (!ROPE) {
#pragma unroll
    for (int mt = 0; mt < 2; mt++)
#pragma unroll
      for (int nt = 0; nt < 2; nt++)
#pragma unroll
        for (int r = 0; r < 4; r++) {
          int row = bm + wm * 32 + mt * 16 + quad * 4 + r;
          int col = bn + wn * 32 + nt * 16 + lr;
          if (F32OUT) ((float*)Cout)[(size_t)row * N + col] = acc[mt][nt][r];
          else ((bf16_t*)Cout)[(size_t)row * N + col] = (bf16_t)acc[mt][nt][r];
        }
  } else {
    // Fused RoPE (k-projection; BN=64 = one head per block). Pair (i, i+32)
    // spans the two wn-waves at same mt/nt/quad/lr/r -> exchange via 16KB fp32
    // scratch overlaying As+Bs (trailing K-loop barrier makes reuse safe).
    float* sc = (float*)smem;   // [64][64] fp32 = 16KB
#pragma unroll
    for (int mt = 0; mt < 2; mt++)
#pragma unroll
      for (int nt = 0; nt < 2; nt++)
#pragma unroll
        for (int r = 0; r < 4; r++) {
          int rl = wm * 32 + mt * 16 + quad * 4 + r;
          int col = wn * 32 + nt * 16 + lr;
          sc[rl * 64 + col] = acc[mt][nt][r];
        }
    __syncthreads();
#pragma unroll
    for (int mt = 0; mt < 2; mt++)
#pragma unroll
      for (int nt = 0; nt < 2; nt++)
#pragma unroll
        for (int r = 0; r < 4; r++) {
          int rl = wm * 32 + mt * 16 + quad * 4 + r;
          int col = wn * 32 + nt * 16 + lr;
          float x = acc[mt][nt][r];
          float y = sc[rl * 64 + (col ^ 32)];
          int i = col & 31;
          float freq = __expf(-0.2878231366f * (float)i);   // 10000^(-i/32)
          float sn, cs;
          sincosf((float)(bm + rl) * freq, &sn, &cs);
          float o = (col < 32) ? (x * cs - y * sn) : (x * cs + y * sn);
          ((bf16_t*)Cout)[(size_t)(bm + rl) * N + bn + col] = (bf16_t)o;
        }
  }
}

// All three projections, one dispatch, 1536 blocks of 64x64 tiles:
// 0..1023:    q  = x Wq^T   (2048x2048: 32x32 tiles)
// 1024..1279: k  = x Wk^T   (2048x512:  32x8,  RoPE fused)
// 1280..1535: vT = Wv x^T   (512x2048:  8x32)
__global__ __launch_bounds__(256) void gemm_proj(const bf16_t* __restrict__ xb,
                                                 const bf16_t* __restrict__ Wqb,
                                                 const bf16_t* __restrict__ Wkb,
                                                 const bf16_t* __restrict__ Wvb,
                                                 bf16_t* __restrict__ qb,
                                                 bf16_t* __restrict__ kb,
                                                 bf16_t* __restrict__ vb) {
  __shared__ __attribute__((aligned(16))) bf16_t smem[2 * 64 * 64];   // 16KB
  int b = blockIdx.x;
  if (b < 1024) {
    gemm_core<false, false>(xb, Wqb, qb, 2048, 2048, (b >> 5) * 64, (b & 31) * 64, smem);
  } else if (b < 1280) {
    int r = b - 1024;
    gemm_core<false, true>(xb, Wkb, kb, 512, 2048, (r >> 3) * 64, (r & 7) * 64, smem);
  } else {
    int r = b - 1280;          // [0,256): vT is 512x2048 -> bm in [0,512)
    gemm_core<false, false>(Wvb, xb, vb, 2048, 2048, (r >> 5) * 64, (r & 31) * 64, smem);
  }
}

// Final projection: out = attn_out Wo^T, fp32 stores. 1024 blocks of 64x64.
__global__ __launch_bounds__(256) void gemm_out(const bf16_t* __restrict__ A,
                                                const bf16_t* __restrict__ Bt,
                                                float* __restrict__ C) {
  __shared__ __attribute__((aligned(16))) bf16_t smem[2 * 64 * 64];   // 16KB
  int b = blockIdx.x;
  gemm_core<true, false>(A, Bt, C, 2048, 2048, (b >> 5) * 64, (b & 31) * 64, smem);
}

// Flash attention, S^T formulation, KB=128 key tiles, 32 q-rows/wave,
// 2-phase double-buffer + setprio. Parked at ~67us: five structural variants
// (R7-R12) all land 67-90us with every pipe <=48% busy -- chain-latency
// plateau for this decomposition. Bit-identical to R5 (best).
__global__ __launch_bounds__(256) void attn_kernel(const bf16_t* __restrict__ q,
                                                   const bf16_t* __restrict__ k,
                                                   const bf16_t* __restrict__ vT,
                                                   bf16_t* __restrict__ out) {
  __shared__ __attribute__((aligned(16))) bf16_t Ks[2][128 * 64];   // [key][d]
  __shared__ __attribute__((aligned(16))) bf16_t Vs[2][64 * 128];   // [d][key]
  const int tid  = threadIdx.x;
  const int wave = tid >> 6, lane = tid & 63;
  const int quad = lane >> 4, lr = lane & 15;
  const int srow = lane >> 3, scol = lane & 7;   // K staging: 8 rows x 8 chunks
  const int vrow = lane >> 4, vcol = lane & 15;  // V staging: 4 rows x 16 chunks
  const int cg = scol ^ srow;                    // K swizzle (row&7 == srow)
  const int qt = blockIdx.x, h = blockIdx.y;
  const int hkv = h >> 2;
  const int qrow0 = qt * 128 + wave * 32;        // 32 q-rows per wave
  const int sw = lr & 7;
  const int c0 = (quad ^ sw) * 8;                // K-frag chunk for d<32
  const int c1 = ((quad + 4) ^ sw) * 8;          // d>=32

  bf16x8 aqA0, aqA1, aqB0, aqB1;
#pragma unroll
  for (int set = 0; set < 2; set++) {
    int row = qrow0 + set * 16 + lr;
    const bf16_t* qp = q + (size_t)row * DMODEL + h * HDIM + quad * 8;
    bf16x8 r0 = *(const bf16x8*)qp;
    bf16x8 r1 = *(const bf16x8*)(qp + 32);
    float srow_f = (float)row;
    bf16x8 a0, a1;
#pragma unroll
    for (int j = 0; j < 8; j++) {
      float freq = __expf(-0.2878231366f * (float)(quad * 8 + j));
      float sn, cs;
      sincosf(srow_f * freq, &sn, &cs);
      float x0 = (float)r0[j], x1 = (float)r1[j];
      a0[j] = (bf16_t)(x0 * cs - x1 * sn);
      a1[j] = (bf16_t)(x1 * cs + x0 * sn);
    }
    if (set == 0) { aqA0 = a0; aqA1 = a1; } else { aqB0 = a0; aqB1 = a1; }
  }

  f32x4 OA[4], OB[4];         // O^T: (d = mt*16+quad*4+r, qrow = lr)
  float lA = 0.f, lB = 0.f;
#pragma unroll
  for (int mt = 0; mt < 4; mt++) { OA[mt] = zero4(); OB[mt] = zero4(); }

#define STAGE_TILE(BUF, KT)                                                              \
  {                                                                                      \
    _Pragma("unroll")                                                                    \
    for (int j = 0; j < 4; j++) {                                                        \
      const bf16_t* gK = k + (size_t)((KT) + wave * 32 + j * 8 + srow) * KVDIM +         \
                         hkv * HDIM + cg * 8;                                            \
      bf16_t* lK = Ks[BUF] + (wave * 32 + j * 8) * 64;                                   \
      __builtin_amdgcn_global_load_lds((const __attribute__((address_space(1))) void*)gK,\
                                       (__attribute__((address_space(3))) void*)lK, 16, 0, 0); \
    }                                                                                    \
    _Pragma("unroll")                                                                    \
    for (int j = 0; j < 4; j++) {                                                        \
      int dg = wave * 16 + j * 4 + vrow;                                                 \
      int cgv = vcol ^ (dg & 7);                                                         \
      const bf16_t* gV = vT + (size_t)(hkv * HDIM + dg) * S_LEN + (KT) + cgv * 8;        \
      bf16_t* lV = Vs[BUF] + (wave * 16 + j * 4) * 128;                                  \
      __builtin_amdgcn_global_load_lds((const __attribute__((address_space(1))) void*)gV,\
                                       (__attribute__((address_space(3))) void*)lV, 16, 0, 0); \
    }                                                                                    \
  }

  STAGE_TILE(0, 0);
  __syncthreads();

  int cur = 0;
  for (int kt = 0; kt < S_LEN; kt += 128) {
    if (kt + 128 < S_LEN) STAGE_TILE(cur ^ 1, kt + 128);
    const bf16_t* Kc = Ks[cur];
    const bf16_t* Vc = Vs[cur];

    s16x4 bpA[8], bpB[8];
#pragma unroll
    for (int nt = 0; nt < 8; nt++) {
      const int rk = (nt * 16 + lr) * 64;
      bf16x8 kb0 = *(const bf16x8*)&Kc[rk + c0];
      bf16x8 kb1 = *(const bf16x8*)&Kc[rk + c1];
      f32x4 sA = zero4(), sB = zero4();
      __builtin_amdgcn_s_setprio(1);
      sA = __builtin_amdgcn_mfma_f32_16x16x32_bf16(kb0, aqA0, sA, 0, 0, 0);
      sA = __builtin_amdgcn_mfma_f32_16x16x32_bf16(kb1, aqA1, sA, 0, 0, 0);
      sB = __builtin_amdgcn_mfma_f32_16x16x32_bf16(kb0, aqB0, sB, 0, 0, 0);
      sB = __builtin_amdgcn_mfma_f32_16x16x32_bf16(kb1, aqB1, sB, 0, 0, 0);
      __builtin_amdgcn_s_setprio(0);
#pragma unroll
      for (int r = 0; r < 4; r++) {
        float pA = __builtin_amdgcn_exp2f(sA[r] * 0.1803368801f);
        lA += pA;
        bpA[nt][r] = __builtin_bit_cast(short, (bf16_t)pA);
        float pB = __builtin_amdgcn_exp2f(sB[r] * 0.1803368801f);
        lB += pB;
        bpB[nt][r] = __builtin_bit_cast(short, (bf16_t)pB);
      }
    }
#pragma unroll
    for (int nt = 0; nt < 8; nt++) {
      const int slot = ((nt * 2 + (quad >> 1)) ^ sw) * 8 + (quad & 1) * 4;
      s16x4 av[4];
#pragma unroll
      for (int mt = 0; mt < 4; mt++)
        av[mt] = *(const s16x4*)&Vc[(mt * 16 + lr) * 128 + slot];
      __builtin_amdgcn_s_setprio(1);
#pragma unroll
      for (int mt = 0; mt < 4; mt++) {
        OA[mt] = __builtin_amdgcn_mfma_f32_16x16x16bf16_1k(av[mt], bpA[nt], OA[mt], 0, 0, 0);
        OB[mt] = __builtin_amdgcn_mfma_f32_16x16x16bf16_1k(av[mt], bpB[nt], OB[mt], 0, 0, 0);
      }
      __builtin_amdgcn_s_setprio(0);
    }
    __syncthreads();
    cur ^= 1;
  }
#undef STAGE_TILE

  lA += __shfl_xor(lA, 16);
  lA += __shfl_xor(lA, 32);
  lB += __shfl_xor(lB, 16);
  lB += __shfl_xor(lB, 32);
  float invA = 1.f / lA;
  float invB = 1.f / lB;

#pragma unroll
  for (int mt = 0; mt < 4; mt++) {
    s16x4 ovA, ovB;
#pragma unroll
    for (int r = 0; r < 4; r++) {
      ovA[r] = __builtin_bit_cast(short, (bf16_t)(OA[mt][r] * invA));
      ovB[r] = __builtin_bit_cast(short, (bf16_t)(OB[mt][r] * invB));
    }
    *(s16x4*)&out[(size_t)(qrow0 + lr) * DMODEL + h * HDIM + mt * 16 + quad * 4] = ovA;
    *(s16x4*)&out[(size_t)(qrow0 + 16 + lr) * DMODEL + h * HDIM + mt * 16 + quad * 4] = ovB;
  }
}

extern "C" void kernel_launch(void* const* d_in, const int* in_sizes, int n_in,
                              void* d_out, int out_size, void* d_ws, size_t ws_size,
                              hipStream_t stream) {
  (void)in_sizes; (void)n_in; (void)out_size; (void)ws_size;
  const float* x  = (const float*)d_in[0];
  const float* Wq = (const float*)d_in[1];
  const float* Wk = (const float*)d_in[2];
  const float* Wv = (const float*)d_in[3];
  const float* Wo = (const float*)d_in[4];

  bf16_t* xb  = (bf16_t*)d_ws;                       // 4M (reused as ab)
  bf16_t* Wqb = xb  + (size_t)4 * 1024 * 1024;       // 4M
  bf16_t* Wkb = Wqb + (size_t)4 * 1024 * 1024;       // 1M
  bf16_t* Wvb = Wkb + (size_t)1024 * 1024;           // 1M
  bf16_t* qb  = Wvb + (size_t)1024 * 1024;           // 4M
  bf16_t* kb  = qb  + (size_t)4 * 1024 * 1024;       // 1M
  bf16_t* vb  = kb  + (size_t)1024 * 1024;           // 1M
  bf16_t* Wob = vb  + (size_t)1024 * 1024;           // 4M (outlives ab=xb)
  bf16_t* ab  = xb;    // x dead after projections

  dim3 blk(256);
  convert_all<<<7168, blk, 0, stream>>>(x, xb, Wq, Wqb, Wk, Wkb, Wv, Wvb, Wo, Wob);
  gemm_proj<<<1536, blk, 0, stream>>>(xb, Wqb, Wkb, Wvb, qb, kb, vb);
  attn_kernel<<<dim3(S_LEN / 128, NHEADS), blk, 0, stream>>>(qb, kb, vb, ab);
  gemm_out<<<1024, blk, 0, stream>>>(ab, Wob, (float*)d_out);
}

// Round 13
// 234.251 us; speedup vs baseline: 1.0470x; 1.0470x over previous
//
#include <hip/hip_runtime.h>
#include <hip/hip_bf16.h>
#include <cmath>

typedef __bf16 bf16_t;
typedef __attribute__((ext_vector_type(8))) __bf16 bf16x8;
typedef __attribute__((ext_vector_type(4))) float f32x4;
typedef __attribute__((ext_vector_type(4))) short s16x4;

#define S_LEN 2048
#define DMODEL 2048
#define KVDIM 512
#define NHEADS 32
#define NKV 8
#define HDIM 64

__device__ inline f32x4 zero4() { f32x4 z; z[0]=0.f; z[1]=0.f; z[2]=0.f; z[3]=0.f; return z; }

// Inputs are fp32 (established R2-R6: bf16 misread would NaN; we pass at 1.46e-3).
// One dispatch converts all 5 tensors to bf16. 2048 elems/block:
// x 2048 | Wq 2048 | Wk 512 | Wv 512 | Wo 2048 blocks (7168 total).
__global__ void convert_all(const float* __restrict__ s0, bf16_t* __restrict__ d0,
                            const float* __restrict__ s1, bf16_t* __restrict__ d1,
                            const float* __restrict__ s2, bf16_t* __restrict__ d2,
                            const float* __restrict__ s3, bf16_t* __restrict__ d3,
                            const float* __restrict__ s4, bf16_t* __restrict__ d4) {
  int b = blockIdx.x;
  const float* src; bf16_t* dst; int boff;
  if      (b < 2048) { src = s0; dst = d0; boff = b; }
  else if (b < 4096) { src = s1; dst = d1; boff = b - 2048; }
  else if (b < 4608) { src = s2; dst = d2; boff = b - 4096; }
  else if (b < 5120) { src = s3; dst = d3; boff = b - 4608; }
  else               { src = s4; dst = d4; boff = b - 5120; }
  int idx = (boff * 256 + threadIdx.x) * 8;
  bf16x8 v;
#pragma unroll
  for (int j = 0; j < 8; j++) v[j] = (bf16_t)src[idx + j];
  *(bf16x8*)(dst + idx) = v;
}

// GEMM core -- R10 configuration (best measured: 234.89us total), restored
// after R12's 64x64-tile experiment regressed to 245.3 (per-block efficiency
// loss beat the TLP gain; closes the tile-size lever). 128 x BN tiles, BK=64,
// 4 waves 2x2, single-buffer LDS, compiler-scheduled waitcnt (manual vmcnt
// CLOSED per R9/m141; split-K, XCD swizzle, drain-0 dbuf all null/regress).
// smem passed in from the __global__ (single allocation across template
// instantiations); ROPE flag fuses k-RoPE into the epilogue via LDS exchange
// (the (i,i+32) pair spans the two wn-waves; trailing K-loop barrier makes the
// scratch reuse safe). rope_k dispatch deleted.
template <int BN, bool F32OUT, bool ROPE>
__device__ __forceinline__ void gemm_core(const bf16_t* __restrict__ A,
                                          const bf16_t* __restrict__ Bt,
                                          void* __restrict__ Cout,
                                          int N, int K, int bm, int bn,
                                          bf16_t* __restrict__ smem) {
  constexpr int NT_W = BN / 32;    // 16-col acc tiles per wave
  bf16_t* As = smem;               // 128 x 64
  bf16_t* Bs = smem + 128 * 64;    // BN x 64
  const int tid  = threadIdx.x;
  const int wave = tid >> 6, lane = tid & 63;
  const int wm = wave >> 1, wn = wave & 1;
  const int quad = lane >> 4, lr = lane & 15;
  const int srow = lane >> 3, scol = lane & 7;

  f32x4 acc[4][NT_W];
#pragma unroll
  for (int i = 0; i < 4; i++)
#pragma unroll
    for (int j = 0; j < NT_W; j++) acc[i][j] = zero4();

  for (int k0 = 0; k0 < K; k0 += 64) {
#pragma unroll
    for (int i = 0; i < 4; i++) {
      const bf16_t* gA = A + (size_t)(bm + i * 32 + wave * 8 + srow) * K + k0 + scol * 8;
      bf16_t* lA = As + (i * 32 + wave * 8) * 64;
      __builtin_amdgcn_global_load_lds((const __attribute__((address_space(1))) void*)gA,
                                       (__attribute__((address_space(3))) void*)lA, 16, 0, 0);
    }
#pragma unroll
    for (int i = 0; i < BN / 32; i++) {
      const bf16_t* gB = Bt + (size_t)(bn + i * 32 + wave * 8 + srow) * K + k0 + scol * 8;
      bf16_t* lB = Bs + (i * 32 + wave * 8) * 64;
      __builtin_amdgcn_global_load_lds((const __attribute__((address_space(1))) void*)gB,
                                       (__attribute__((address_space(3))) void*)lB, 16, 0, 0);
    }
    __syncthreads();
#pragma unroll
    for (int ks = 0; ks < 2; ks++) {
      bf16x8 a[4], b[NT_W];
#pragma unroll
      for (int mt = 0; mt < 4; mt++)
        a[mt] = *(const bf16x8*)&As[(wm * 64 + mt * 16 + lr) * 64 + ks * 32 + quad * 8];
#pragma unroll
      for (int nt = 0; nt < NT_W; nt++)
        b[nt] = *(const bf16x8*)&Bs[(wn * (BN / 2) + nt * 16 + lr) * 64 + ks * 32 + quad * 8];
#pragma unroll
      for (int mt = 0; mt < 4; mt++)
#pragma unroll
        for (int nt = 0; nt < NT_W; nt++)
          acc[mt][nt] = __builtin_amdgcn_mfma_f32_16x16x32_bf16(a[mt], b[nt], acc[mt][nt], 0, 0, 0);
    }
    __syncthreads();
  }

  if (!ROPE) {
#pragma unroll
    for (int mt = 0; mt < 4; mt++)
#pragma unroll
      for (int nt = 0; nt < NT_W; nt++)
#pragma unroll
        for (int r = 0; r < 4; r++) {
          int row = bm + wm * 64 + mt * 16 + quad * 4 + r;
          int col = bn + wn * (BN / 2) + nt * 16 + lr;
          if (F32OUT) ((float*)Cout)[(size_t)row * N + col] = acc[mt][nt][r];
          else ((bf16_t*)Cout)[(size_t)row * N + col] = (bf16_t)acc[mt][nt][r];
        }
  } else {
    // Fused RoPE (k-projection, BN=64: one 64-col head per block). Pair
    // (i, i+32) lives in waves (wm,0)/(wm,1) at identical mt/nt/quad/lr/r ->
    // exchange through 32KB fp32 scratch overlaying As+Bs (trailing K-loop
    // __syncthreads guarantees all LDS reads done).
    float* sc = (float*)smem;   // [128][64] fp32 = 32KB
#pragma unroll
    for (int mt = 0; mt < 4; mt++)
#pragma unroll
      for (int nt = 0; nt < NT_W; nt++)
#pragma unroll
        for (int r = 0; r < 4; r++) {
          int rl = wm * 64 + mt * 16 + quad * 4 + r;
          int col = wn * (BN / 2) + nt * 16 + lr;
          sc[rl * 64 + col] = acc[mt][nt][r];
        }
    __syncthreads();
#pragma unroll
    for (int mt = 0; mt < 4; mt++)
#pragma unroll
      for (int nt = 0; nt < NT_W; nt++)
#pragma unroll
        for (int r = 0; r < 4; r++) {
          int rl = wm * 64 + mt * 16 + quad * 4 + r;
          int col = wn * (BN / 2) + nt * 16 + lr;
          float x = acc[mt][nt][r];
          float y = sc[rl * 64 + (col ^ 32)];
          int i = col & 31;
          float freq = __expf(-0.2878231366f * (float)i);   // 10000^(-i/32)
          float sn, cs;
          sincosf((float)(bm + rl) * freq, &sn, &cs);
          float o = (col < 32) ? (x * cs - y * sn) : (x * cs + y * sn);
          ((bf16_t*)Cout)[(size_t)(bm + rl) * N + bn + col] = (bf16_t)o;
        }
  }
}

// All three projections, one dispatch, 768 blocks of 128x64 tiles:
// 0..511: q = x Wq^T; 512..639: k = x Wk^T (RoPE fused); 640..767: vT = Wv x^T.
__global__ __launch_bounds__(256) void gemm_proj(const bf16_t* __restrict__ xb,
                                                 const bf16_t* __restrict__ Wqb,
                                                 const bf16_t* __restrict__ Wkb,
                                                 const bf16_t* __restrict__ Wvb,
                                                 bf16_t* __restrict__ qb,
                                                 bf16_t* __restrict__ kb,
                                                 bf16_t* __restrict__ vb) {
  // 32KB: As(16K)+Bs(8K) for the main loop; full 32KB fp32 scratch for RoPE.
  __shared__ __attribute__((aligned(16))) bf16_t smem[128 * 64 + 64 * 64 + 64 * 64];
  int b = blockIdx.x;
  if (b < 512) {
    gemm_core<64, false, false>(xb, Wqb, qb, 2048, 2048, (b >> 5) * 128, (b & 31) * 64, smem);
  } else if (b < 640) {
    int r = b - 512;
    gemm_core<64, false, true>(xb, Wkb, kb, 512, 2048, (r >> 3) * 128, (r & 7) * 64, smem);
  } else {
    int r = b - 640;
    gemm_core<64, false, false>(Wvb, xb, vb, 2048, 2048, (r >> 5) * 128, (r & 31) * 64, smem);
  }
}

// Final projection: out = attn_out Wo^T, fp32 stores. 512 blocks of 128x64.
__global__ __launch_bounds__(256) void gemm_out(const bf16_t* __restrict__ A,
                                                const bf16_t* __restrict__ Bt,
                                                float* __restrict__ C) {
  __shared__ __attribute__((aligned(16))) bf16_t smem[128 * 64 + 64 * 64];
  int b = blockIdx.x;
  gemm_core<64, true, false>(A, Bt, C, 2048, 2048, (b >> 5) * 128, (b & 31) * 64, smem);
}

// Flash attention, S^T formulation, KB=128 key tiles, 32 q-rows/wave,
// 2-phase double-buffer + setprio. Parked at ~67us: five structural variants
// (R7-R12) all land 67-90us with every pipe <=48% busy -- chain-latency
// plateau for this decomposition. Bit-identical to R5/R10 (best: 234.89us).
__global__ __launch_bounds__(256) void attn_kernel(const bf16_t* __restrict__ q,
                                                   const bf16_t* __restrict__ k,
                                                   const bf16_t* __restrict__ vT,
                                                   bf16_t* __restrict__ out) {
  __shared__ __attribute__((aligned(16))) bf16_t Ks[2][128 * 64];   // [key][d]
  __shared__ __attribute__((aligned(16))) bf16_t Vs[2][64 * 128];   // [d][key]
  const int tid  = threadIdx.x;
  const int wave = tid >> 6, lane = tid & 63;
  const int quad = lane >> 4, lr = lane & 15;
  const int srow = lane >> 3, scol = lane & 7;   // K staging: 8 rows x 8 chunks
  const int vrow = lane >> 4, vcol = lane & 15;  // V staging: 4 rows x 16 chunks
  const int cg = scol ^ srow;                    // K swizzle (row&7 == srow)
  const int qt = blockIdx.x, h = blockIdx.y;
  const int hkv = h >> 2;
  const int qrow0 = qt * 128 + wave * 32;        // 32 q-rows per wave
  const int sw = lr & 7;
  const int c0 = (quad ^ sw) * 8;                // K-frag chunk for d<32
  const int c1 = ((quad + 4) ^ sw) * 8;          // d>=32

  bf16x8 aqA0, aqA1, aqB0, aqB1;
#pragma unroll
  for (int set = 0; set < 2; set++) {
    int row = qrow0 + set * 16 + lr;
    const bf16_t* qp = q + (size_t)row * DMODEL + h * HDIM + quad * 8;
    bf16x8 r0 = *(const bf16x8*)qp;
    bf16x8 r1 = *(const bf16x8*)(qp + 32);
    float srow_f = (float)row;
    bf16x8 a0, a1;
#pragma unroll
    for (int j = 0; j < 8; j++) {
      float freq = __expf(-0.2878231366f * (float)(quad * 8 + j));
      float sn, cs;
      sincosf(srow_f * freq, &sn, &cs);
      float x0 = (float)r0[j], x1 = (float)r1[j];
      a0[j] = (bf16_t)(x0 * cs - x1 * sn);
      a1[j] = (bf16_t)(x1 * cs + x0 * sn);
    }
    if (set == 0) { aqA0 = a0; aqA1 = a1; } else { aqB0 = a0; aqB1 = a1; }
  }

  f32x4 OA[4], OB[4];         // O^T: (d = mt*16+quad*4+r, qrow = lr)
  float lA = 0.f, lB = 0.f;
#pragma unroll
  for (int mt = 0; mt < 4; mt++) { OA[mt] = zero4(); OB[mt] = zero4(); }

#define STAGE_TILE(BUF, KT)                                                              \
  {                                                                                      \
    _Pragma("unroll")                                                                    \
    for (int j = 0; j < 4; j++) {                                                        \
      const bf16_t* gK = k + (size_t)((KT) + wave * 32 + j * 8 + srow) * KVDIM +         \
                         hkv * HDIM + cg * 8;                                            \
      bf16_t* lK = Ks[BUF] + (wave * 32 + j * 8) * 64;                                   \
      __builtin_amdgcn_global_load_lds((const __attribute__((address_space(1))) void*)gK,\
                                       (__attribute__((address_space(3))) void*)lK, 16, 0, 0); \
    }                                                                                    \
    _Pragma("unroll")                                                                    \
    for (int j = 0; j < 4; j++) {                                                        \
      int dg = wave * 16 + j * 4 + vrow;                                                 \
      int cgv = vcol ^ (dg & 7);                                                         \
      const bf16_t* gV = vT + (size_t)(hkv * HDIM + dg) * S_LEN + (KT) + cgv * 8;        \
      bf16_t* lV = Vs[BUF] + (wave * 16 + j * 4) * 128;                                  \
      __builtin_amdgcn_global_load_lds((const __attribute__((address_space(1))) void*)gV,\
                                       (__attribute__((address_space(3))) void*)lV, 16, 0, 0); \
    }                                                                                    \
  }

  STAGE_TILE(0, 0);
  __syncthreads();

  int cur = 0;
  for (int kt = 0; kt < S_LEN; kt += 128) {
    if (kt + 128 < S_LEN) STAGE_TILE(cur ^ 1, kt + 128);
    const bf16_t* Kc = Ks[cur];
    const bf16_t* Vc = Vs[cur];

    s16x4 bpA[8], bpB[8];
#pragma unroll
    for (int nt = 0; nt < 8; nt++) {
      const int rk = (nt * 16 + lr) * 64;
      bf16x8 kb0 = *(const bf16x8*)&Kc[rk + c0];
      bf16x8 kb1 = *(const bf16x8*)&Kc[rk + c1];
      f32x4 sA = zero4(), sB = zero4();
      __builtin_amdgcn_s_setprio(1);
      sA = __builtin_amdgcn_mfma_f32_16x16x32_bf16(kb0, aqA0, sA, 0, 0, 0);
      sA = __builtin_amdgcn_mfma_f32_16x16x32_bf16(kb1, aqA1, sA, 0, 0, 0);
      sB = __builtin_amdgcn_mfma_f32_16x16x32_bf16(kb0, aqB0, sB, 0, 0, 0);
      sB = __builtin_amdgcn_mfma_f32_16x16x32_bf16(kb1, aqB1, sB, 0, 0, 0);
      __builtin_amdgcn_s_setprio(0);
#pragma unroll
      for (int r = 0; r < 4; r++) {
        float pA = __builtin_amdgcn_exp2f(sA[r] * 0.1803368801f);
        lA += pA;
        bpA[nt][r] = __builtin_bit_cast(short, (bf16_t)pA);
        float pB = __builtin_amdgcn_exp2f(sB[r] * 0.1803368801f);
        lB += pB;
        bpB[nt][r] = __builtin_bit_cast(short, (bf16_t)pB);
      }
    }
#pragma unroll
    for (int nt = 0; nt < 8; nt++) {
      const int slot = ((nt * 2 + (quad >> 1)) ^ sw) * 8 + (quad & 1) * 4;
      s16x4 av[4];
#pragma unroll
      for (int mt = 0; mt < 4; mt++)
        av[mt] = *(const s16x4*)&Vc[(mt * 16 + lr) * 128 + slot];
      __builtin_amdgcn_s_setprio(1);
#pragma unroll
      for (int mt = 0; mt < 4; mt++) {
        OA[mt] = __builtin_amdgcn_mfma_f32_16x16x16bf16_1k(av[mt], bpA[nt], OA[mt], 0, 0, 0);
        OB[mt] = __builtin_amdgcn_mfma_f32_16x16x16bf16_1k(av[mt], bpB[nt], OB[mt], 0, 0, 0);
      }
      __builtin_amdgcn_s_setprio(0);
    }
    __syncthreads();
    cur ^= 1;
  }
#undef STAGE_TILE

  lA += __shfl_xor(lA, 16);
  lA += __shfl_xor(lA, 32);
  lB += __shfl_xor(lB, 16);
  lB += __shfl_xor(lB, 32);
  float invA = 1.f / lA;
  float invB = 1.f / lB;

#pragma unroll
  for (int mt = 0; mt < 4; mt++) {
    s16x4 ovA, ovB;
#pragma unroll
    for (int r = 0; r < 4; r++) {
      ovA[r] = __builtin_bit_cast(short, (bf16_t)(OA[mt][r] * invA));
      ovB[r] = __builtin_bit_cast(short, (bf16_t)(OB[mt][r] * invB));
    }
    *(s16x4*)&out[(size_t)(qrow0 + lr) * DMODEL + h * HDIM + mt * 16 + quad * 4] = ovA;
    *(s16x4*)&out[(size_t)(qrow0 + 16 + lr) * DMODEL + h * HDIM + mt * 16 + quad * 4] = ovB;
  }
}

extern "C" void kernel_launch(void* const* d_in, const int* in_sizes, int n_in,
                              void* d_out, int out_size, void* d_ws, size_t ws_size,
                              hipStream_t stream) {
  (void)in_sizes; (void)n_in; (void)out_size; (void)ws_size;
  const float* x  = (const float*)d_in[0];
  const float* Wq = (const float*)d_in[1];
  const float* Wk = (const float*)d_in[2];
  const float* Wv = (const float*)d_in[3];
  const float* Wo = (const float*)d_in[4];

  bf16_t* xb  = (bf16_t*)d_ws;                       // 4M (reused as ab)
  bf16_t* Wqb = xb  + (size_t)4 * 1024 * 1024;       // 4M
  bf16_t* Wkb = Wqb + (size_t)4 * 1024 * 1024;       // 1M
  bf16_t* Wvb = Wkb + (size_t)1024 * 1024;           // 1M
  bf16_t* qb  = Wvb + (size_t)1024 * 1024;           // 4M
  bf16_t* kb  = qb  + (size_t)4 * 1024 * 1024;       // 1M
  bf16_t* vb  = kb  + (size_t)1024 * 1024;           // 1M
  bf16_t* Wob = vb  + (size_t)1024 * 1024;           // 4M (outlives ab=xb)
  bf16_t* ab  = xb;    // x dead after projections

  dim3 blk(256);
  convert_all<<<7168, blk, 0, stream>>>(x, xb, Wq, Wqb, Wk, Wkb, Wv, Wvb, Wo, Wob);
  gemm_proj<<<768, blk, 0, stream>>>(xb, Wqb, Wkb, Wvb, qb, kb, vb);
  attn_kernel<<<dim3(S_LEN / 128, NHEADS), blk, 0, stream>>>(qb, kb, vb, ab);
  gemm_out<<<512, blk, 0, stream>>>(ab, Wob, (float*)d_out);
}

// Round 14
// 230.465 us; speedup vs baseline: 1.0642x; 1.0164x over previous
//
#include <hip/hip_runtime.h>
#include <hip/hip_bf16.h>
#include <cmath>

typedef __bf16 bf16_t;
typedef __attribute__((ext_vector_type(8))) __bf16 bf16x8;
typedef __attribute__((ext_vector_type(4))) float f32x4;
typedef __attribute__((ext_vector_type(4))) short s16x4;

#define S_LEN 2048
#define DMODEL 2048
#define KVDIM 512
#define NHEADS 32
#define NKV 8
#define HDIM 64

__device__ inline f32x4 zero4() { f32x4 z; z[0]=0.f; z[1]=0.f; z[2]=0.f; z[3]=0.f; return z; }

// Inputs are fp32 (established R2-R6: bf16 misread would NaN; we pass at 1.46e-3).
// One dispatch converts all 5 tensors to bf16. 2048 elems/block:
// x 2048 | Wq 2048 | Wk 512 | Wv 512 | Wo 2048 blocks (7168 total).
__global__ void convert_all(const float* __restrict__ s0, bf16_t* __restrict__ d0,
                            const float* __restrict__ s1, bf16_t* __restrict__ d1,
                            const float* __restrict__ s2, bf16_t* __restrict__ d2,
                            const float* __restrict__ s3, bf16_t* __restrict__ d3,
                            const float* __restrict__ s4, bf16_t* __restrict__ d4) {
  int b = blockIdx.x;
  const float* src; bf16_t* dst; int boff;
  if      (b < 2048) { src = s0; dst = d0; boff = b; }
  else if (b < 4096) { src = s1; dst = d1; boff = b - 2048; }
  else if (b < 4608) { src = s2; dst = d2; boff = b - 4096; }
  else if (b < 5120) { src = s3; dst = d3; boff = b - 4608; }
  else               { src = s4; dst = d4; boff = b - 5120; }
  int idx = (boff * 256 + threadIdx.x) * 8;
  bf16x8 v;
#pragma unroll
  for (int j = 0; j < 8; j++) v[j] = (bf16_t)src[idx + j];
  *(bf16x8*)(dst + idx) = v;
}

// GEMM core -- R10 configuration (best measured: 234.25us total). 128 x BN
// tiles, BK=64, 4 waves 2x2, single-buffer LDS, compiler-scheduled waitcnt
// (manual vmcnt CLOSED per R9/m141; split-K, XCD swizzle, drain-0 dbuf,
// 64x64 tiles all null/regress). R13 timestamp analysis: gemm_out + convert +
// gemm_proj + gaps all fit in 54.6us -- the GEMMs are near their m102-family
// expectation and are NOT the dominant cost (attn is, at 55%).
// ROPE flag fuses k-RoPE into the epilogue via LDS exchange.
template <int BN, bool F32OUT, bool ROPE>
__device__ __forceinline__ void gemm_core(const bf16_t* __restrict__ A,
                                          const bf16_t* __restrict__ Bt,
                                          void* __restrict__ Cout,
                                          int N, int K, int bm, int bn,
                                          bf16_t* __restrict__ smem) {
  constexpr int NT_W = BN / 32;    // 16-col acc tiles per wave
  bf16_t* As = smem;               // 128 x 64
  bf16_t* Bs = smem + 128 * 64;    // BN x 64
  const int tid  = threadIdx.x;
  const int wave = tid >> 6, lane = tid & 63;
  const int wm = wave >> 1, wn = wave & 1;
  const int quad = lane >> 4, lr = lane & 15;
  const int srow = lane >> 3, scol = lane & 7;

  f32x4 acc[4][NT_W];
#pragma unroll
  for (int i = 0; i < 4; i++)
#pragma unroll
    for (int j = 0; j < NT_W; j++) acc[i][j] = zero4();

  for (int k0 = 0; k0 < K; k0 += 64) {
#pragma unroll
    for (int i = 0; i < 4; i++) {
      const bf16_t* gA = A + (size_t)(bm + i * 32 + wave * 8 + srow) * K + k0 + scol * 8;
      bf16_t* lA = As + (i * 32 + wave * 8) * 64;
      __builtin_amdgcn_global_load_lds((const __attribute__((address_space(1))) void*)gA,
                                       (__attribute__((address_space(3))) void*)lA, 16, 0, 0);
    }
#pragma unroll
    for (int i = 0; i < BN / 32; i++) {
      const bf16_t* gB = Bt + (size_t)(bn + i * 32 + wave * 8 + srow) * K + k0 + scol * 8;
      bf16_t* lB = Bs + (i * 32 + wave * 8) * 64;
      __builtin_amdgcn_global_load_lds((const __attribute__((address_space(1))) void*)gB,
                                       (__attribute__((address_space(3))) void*)lB, 16, 0, 0);
    }
    __syncthreads();
#pragma unroll
    for (int ks = 0; ks < 2; ks++) {
      bf16x8 a[4], b[NT_W];
#pragma unroll
      for (int mt = 0; mt < 4; mt++)
        a[mt] = *(const bf16x8*)&As[(wm * 64 + mt * 16 + lr) * 64 + ks * 32 + quad * 8];
#pragma unroll
      for (int nt = 0; nt < NT_W; nt++)
        b[nt] = *(const bf16x8*)&Bs[(wn * (BN / 2) + nt * 16 + lr) * 64 + ks * 32 + quad * 8];
#pragma unroll
      for (int mt = 0; mt < 4; mt++)
#pragma unroll
        for (int nt = 0; nt < NT_W; nt++)
          acc[mt][nt] = __builtin_amdgcn_mfma_f32_16x16x32_bf16(a[mt], b[nt], acc[mt][nt], 0, 0, 0);
    }
    __syncthreads();
  }

  if (!ROPE) {
#pragma unroll
    for (int mt = 0; mt < 4; mt++)
#pragma unroll
      for (int nt = 0; nt < NT_W; nt++)
#pragma unroll
        for (int r = 0; r < 4; r++) {
          int row = bm + wm * 64 + mt * 16 + quad * 4 + r;
          int col = bn + wn * (BN / 2) + nt * 16 + lr;
          if (F32OUT) ((float*)Cout)[(size_t)row * N + col] = acc[mt][nt][r];
          else ((bf16_t*)Cout)[(size_t)row * N + col] = (bf16_t)acc[mt][nt][r];
        }
  } else {
    // Fused RoPE (k-projection, BN=64: one 64-col head per block). Pair
    // (i, i+32) lives in waves (wm,0)/(wm,1) at identical mt/nt/quad/lr/r ->
    // exchange through 32KB fp32 scratch overlaying As+Bs (trailing K-loop
    // __syncthreads guarantees all LDS reads done).
    float* sc = (float*)smem;   // [128][64] fp32 = 32KB
#pragma unroll
    for (int mt = 0; mt < 4; mt++)
#pragma unroll
      for (int nt = 0; nt < NT_W; nt++)
#pragma unroll
        for (int r = 0; r < 4; r++) {
          int rl = wm * 64 + mt * 16 + quad * 4 + r;
          int col = wn * (BN / 2) + nt * 16 + lr;
          sc[rl * 64 + col] = acc[mt][nt][r];
        }
    __syncthreads();
#pragma unroll
    for (int mt = 0; mt < 4; mt++)
#pragma unroll
      for (int nt = 0; nt < NT_W; nt++)
#pragma unroll
        for (int r = 0; r < 4; r++) {
          int rl = wm * 64 + mt * 16 + quad * 4 + r;
          int col = wn * (BN / 2) + nt * 16 + lr;
          float x = acc[mt][nt][r];
          float y = sc[rl * 64 + (col ^ 32)];
          int i = col & 31;
          float freq = __expf(-0.2878231366f * (float)i);   // 10000^(-i/32)
          float sn, cs;
          sincosf((float)(bm + rl) * freq, &sn, &cs);
          float o = (col < 32) ? (x * cs - y * sn) : (x * cs + y * sn);
          ((bf16_t*)Cout)[(size_t)(bm + rl) * N + bn + col] = (bf16_t)o;
        }
  }
}

// All three projections, one dispatch, 768 blocks of 128x64 tiles:
// 0..511: q = x Wq^T; 512..639: k = x Wk^T (RoPE fused); 640..767: vT = Wv x^T.
__global__ __launch_bounds__(256) void gemm_proj(const bf16_t* __restrict__ xb,
                                                 const bf16_t* __restrict__ Wqb,
                                                 const bf16_t* __restrict__ Wkb,
                                                 const bf16_t* __restrict__ Wvb,
                                                 bf16_t* __restrict__ qb,
                                                 bf16_t* __restrict__ kb,
                                                 bf16_t* __restrict__ vb) {
  // 32KB: As(16K)+Bs(8K) for the main loop; full 32KB fp32 scratch for RoPE.
  __shared__ __attribute__((aligned(16))) bf16_t smem[128 * 64 + 64 * 64 + 64 * 64];
  int b = blockIdx.x;
  if (b < 512) {
    gemm_core<64, false, false>(xb, Wqb, qb, 2048, 2048, (b >> 5) * 128, (b & 31) * 64, smem);
  } else if (b < 640) {
    int r = b - 512;
    gemm_core<64, false, true>(xb, Wkb, kb, 512, 2048, (r >> 3) * 128, (r & 7) * 64, smem);
  } else {
    int r = b - 640;
    gemm_core<64, false, false>(Wvb, xb, vb, 2048, 2048, (r >> 5) * 128, (r & 31) * 64, smem);
  }
}

// Final projection: out = attn_out Wo^T, fp32 stores. 512 blocks of 128x64.
__global__ __launch_bounds__(256) void gemm_out(const bf16_t* __restrict__ A,
                                                const bf16_t* __restrict__ Bt,
                                                float* __restrict__ C) {
  __shared__ __attribute__((aligned(16))) bf16_t smem[128 * 64 + 64 * 64];
  int b = blockIdx.x;
  gemm_core<64, true, false>(A, Bt, C, 2048, 2048, (b >> 5) * 128, (b & 31) * 64, smem);
}

// Flash attention, S^T formulation, KB=128 key tiles, 32 q-rows/wave,
// 2-phase double-buffer + setprio. R14 change: QK -> exp -> PV FUSED PER
// KEY-SUBTILE (one nt-loop instead of two). Mechanism: (a) K-b128 and V-b64
// LDS reads interleave evenly instead of two per-tile bursts (lower LDS-queue
// peaks -- LDS runs at ~61 B/cy/CU, ~70% of the m134 practical ceiling);
// (b) bp live range drops whole-tile -> per-nt (VGPR 88 -> ~56), freeing the
// scheduler to pipeline across nt; (c) exp (trans pipe) sits between MFMA
// clusters of adjacent nt -> VALU||MFMA overlap within one wave.
// Zero index/layout changes -- pure loop-merge of the verified R13 code.
__global__ __launch_bounds__(256) void attn_kernel(const bf16_t* __restrict__ q,
                                                   const bf16_t* __restrict__ k,
                                                   const bf16_t* __restrict__ vT,
                                                   bf16_t* __restrict__ out) {
  __shared__ __attribute__((aligned(16))) bf16_t Ks[2][128 * 64];   // [key][d]
  __shared__ __attribute__((aligned(16))) bf16_t Vs[2][64 * 128];   // [d][key]
  const int tid  = threadIdx.x;
  const int wave = tid >> 6, lane = tid & 63;
  const int quad = lane >> 4, lr = lane & 15;
  const int srow = lane >> 3, scol = lane & 7;   // K staging: 8 rows x 8 chunks
  const int vrow = lane >> 4, vcol = lane & 15;  // V staging: 4 rows x 16 chunks
  const int cg = scol ^ srow;                    // K swizzle (row&7 == srow)
  const int qt = blockIdx.x, h = blockIdx.y;
  const int hkv = h >> 2;
  const int qrow0 = qt * 128 + wave * 32;        // 32 q-rows per wave
  const int sw = lr & 7;
  const int c0 = (quad ^ sw) * 8;                // K-frag chunk for d<32
  const int c1 = ((quad + 4) ^ sw) * 8;          // d>=32

  bf16x8 aqA0, aqA1, aqB0, aqB1;
#pragma unroll
  for (int set = 0; set < 2; set++) {
    int row = qrow0 + set * 16 + lr;
    const bf16_t* qp = q + (size_t)row * DMODEL + h * HDIM + quad * 8;
    bf16x8 r0 = *(const bf16x8*)qp;
    bf16x8 r1 = *(const bf16x8*)(qp + 32);
    float srow_f = (float)row;
    bf16x8 a0, a1;
#pragma unroll
    for (int j = 0; j < 8; j++) {
      float freq = __expf(-0.2878231366f * (float)(quad * 8 + j));
      float sn, cs;
      sincosf(srow_f * freq, &sn, &cs);
      float x0 = (float)r0[j], x1 = (float)r1[j];
      a0[j] = (bf16_t)(x0 * cs - x1 * sn);
      a1[j] = (bf16_t)(x1 * cs + x0 * sn);
    }
    if (set == 0) { aqA0 = a0; aqA1 = a1; } else { aqB0 = a0; aqB1 = a1; }
  }

  f32x4 OA[4], OB[4];         // O^T: (d = mt*16+quad*4+r, qrow = lr)
  float lA = 0.f, lB = 0.f;
#pragma unroll
  for (int mt = 0; mt < 4; mt++) { OA[mt] = zero4(); OB[mt] = zero4(); }

#define STAGE_TILE(BUF, KT)                                                              \
  {                                                                                      \
    _Pragma("unroll")                                                                    \
    for (int j = 0; j < 4; j++) {                                                        \
      const bf16_t* gK = k + (size_t)((KT) + wave * 32 + j * 8 + srow) * KVDIM +         \
                         hkv * HDIM + cg * 8;                                            \
      bf16_t* lK = Ks[BUF] + (wave * 32 + j * 8) * 64;                                   \
      __builtin_amdgcn_global_load_lds((const __attribute__((address_space(1))) void*)gK,\
                                       (__attribute__((address_space(3))) void*)lK, 16, 0, 0); \
    }                                                                                    \
    _Pragma("unroll")                                                                    \
    for (int j = 0; j < 4; j++) {                                                        \
      int dg = wave * 16 + j * 4 + vrow;                                                 \
      int cgv = vcol ^ (dg & 7);                                                         \
      const bf16_t* gV = vT + (size_t)(hkv * HDIM + dg) * S_LEN + (KT) + cgv * 8;        \
      bf16_t* lV = Vs[BUF] + (wave * 16 + j * 4) * 128;                                  \
      __builtin_amdgcn_global_load_lds((const __attribute__((address_space(1))) void*)gV,\
                                       (__attribute__((address_space(3))) void*)lV, 16, 0, 0); \
    }                                                                                    \
  }

  STAGE_TILE(0, 0);
  __syncthreads();

  int cur = 0;
  for (int kt = 0; kt < S_LEN; kt += 128) {
    if (kt + 128 < S_LEN) STAGE_TILE(cur ^ 1, kt + 128);
    const bf16_t* Kc = Ks[cur];
    const bf16_t* Vc = Vs[cur];

    // Fused per-nt: QK (4 MFMA) -> exp (8 trans) -> PV (4 b64 + 8 MFMA).
#pragma unroll
    for (int nt = 0; nt < 8; nt++) {
      const int rk = (nt * 16 + lr) * 64;
      bf16x8 kb0 = *(const bf16x8*)&Kc[rk + c0];
      bf16x8 kb1 = *(const bf16x8*)&Kc[rk + c1];
      f32x4 sA = zero4(), sB = zero4();
      __builtin_amdgcn_s_setprio(1);
      sA = __builtin_amdgcn_mfma_f32_16x16x32_bf16(kb0, aqA0, sA, 0, 0, 0);
      sA = __builtin_amdgcn_mfma_f32_16x16x32_bf16(kb1, aqA1, sA, 0, 0, 0);
      sB = __builtin_amdgcn_mfma_f32_16x16x32_bf16(kb0, aqB0, sB, 0, 0, 0);
      sB = __builtin_amdgcn_mfma_f32_16x16x32_bf16(kb1, aqB1, sB, 0, 0, 0);
      __builtin_amdgcn_s_setprio(0);
      s16x4 bpA, bpB;
#pragma unroll
      for (int r = 0; r < 4; r++) {
        float pA = __builtin_amdgcn_exp2f(sA[r] * 0.1803368801f);
        lA += pA;
        bpA[r] = __builtin_bit_cast(short, (bf16_t)pA);
        float pB = __builtin_amdgcn_exp2f(sB[r] * 0.1803368801f);
        lB += pB;
        bpB[r] = __builtin_bit_cast(short, (bf16_t)pB);
      }
      const int slot = ((nt * 2 + (quad >> 1)) ^ sw) * 8 + (quad & 1) * 4;
      s16x4 av[4];
#pragma unroll
      for (int mt = 0; mt < 4; mt++)
        av[mt] = *(const s16x4*)&Vc[(mt * 16 + lr) * 128 + slot];
      __builtin_amdgcn_s_setprio(1);
#pragma unroll
      for (int mt = 0; mt < 4; mt++) {
        OA[mt] = __builtin_amdgcn_mfma_f32_16x16x16bf16_1k(av[mt], bpA, OA[mt], 0, 0, 0);
        OB[mt] = __builtin_amdgcn_mfma_f32_16x16x16bf16_1k(av[mt], bpB, OB[mt], 0, 0, 0);
      }
      __builtin_amdgcn_s_setprio(0);
    }
    __syncthreads();
    cur ^= 1;
  }
#undef STAGE_TILE

  lA += __shfl_xor(lA, 16);
  lA += __shfl_xor(lA, 32);
  lB += __shfl_xor(lB, 16);
  lB += __shfl_xor(lB, 32);
  float invA = 1.f / lA;
  float invB = 1.f / lB;

#pragma unroll
  for (int mt = 0; mt < 4; mt++) {
    s16x4 ovA, ovB;
#pragma unroll
    for (int r = 0; r < 4; r++) {
      ovA[r] = __builtin_bit_cast(short, (bf16_t)(OA[mt][r] * invA));
      ovB[r] = __builtin_bit_cast(short, (bf16_t)(OB[mt][r] * invB));
    }
    *(s16x4*)&out[(size_t)(qrow0 + lr) * DMODEL + h * HDIM + mt * 16 + quad * 4] = ovA;
    *(s16x4*)&out[(size_t)(qrow0 + 16 + lr) * DMODEL + h * HDIM + mt * 16 + quad * 4] = ovB;
  }
}

extern "C" void kernel_launch(void* const* d_in, const int* in_sizes, int n_in,
                              void* d_out, int out_size, void* d_ws, size_t ws_size,
                              hipStream_t stream) {
  (void)in_sizes; (void)n_in; (void)out_size; (void)ws_size;
  const float* x  = (const float*)d_in[0];
  const float* Wq = (const float*)d_in[1];
  const float* Wk = (const float*)d_in[2];
  const float* Wv = (const float*)d_in[3];
  const float* Wo = (const float*)d_in[4];

  bf16_t* xb  = (bf16_t*)d_ws;                       // 4M (reused as ab)
  bf16_t* Wqb = xb  + (size_t)4 * 1024 * 1024;       // 4M
  bf16_t* Wkb = Wqb + (size_t)4 * 1024 * 1024;       // 1M
  bf16_t* Wvb = Wkb + (size_t)1024 * 1024;           // 1M
  bf16_t* qb  = Wvb + (size_t)1024 * 1024;           // 4M
  bf16_t* kb  = qb  + (size_t)4 * 1024 * 1024;       // 1M
  bf16_t* vb  = kb  + (size_t)1024 * 1024;           // 1M
  bf16_t* Wob = vb  + (size_t)1024 * 1024;           // 4M (outlives ab=xb)
  bf16_t* ab  = xb;    // x dead after projections

  dim3 blk(256);
  convert_all<<<7168, blk, 0, stream>>>(x, xb, Wq, Wqb, Wk, Wkb, Wv, Wvb, Wo, Wob);
  gemm_proj<<<768, blk, 0, stream>>>(xb, Wqb, Wkb, Wvb, qb, kb, vb);
  attn_kernel<<<dim3(S_LEN / 128, NHEADS), blk, 0, stream>>>(qb, kb, vb, ab);
  gemm_out<<<512, blk, 0, stream>>>(ab, Wob, (float*)d_out);
}